// Round 7
// baseline (170.469 us; speedup 1.0000x reference)
//
#include <hip/hip_runtime.h>
#include <stdint.h>

#define DIM 256
#define NEMB 8192
#define NTOK 16384
#define HW 1024

typedef __attribute__((ext_vector_type(4))) int int4v;

// ---- helpers ----
__device__ __forceinline__ void async_cp16(void* lds, const void* g) {
  __builtin_amdgcn_global_load_lds(
      (const __attribute__((address_space(1))) unsigned int*)g,
      (__attribute__((address_space(3))) unsigned int*)lds, 16, 0, 0);
}
// x ~ s*(q0 + q1/128), s = 1/20
__device__ __forceinline__ int q0_of(float x) {
  int q = __float2int_rn(x * 20.0f);
  return q > 127 ? 127 : (q < -127 ? -127 : q);
}
__device__ __forceinline__ int q1_of(float x, int q0) {
  float e = x * 20.0f - (float)q0;
  int q = __float2int_rn(e * 128.0f);
  return q > 127 ? 127 : (q < -127 ? -127 : q);
}
__device__ __forceinline__ unsigned int pack4(int a, int b, int c, int d) {
  return (unsigned int)(a & 0xff) | ((unsigned int)(b & 0xff) << 8) |
         ((unsigned int)(c & 0xff) << 16) | ((unsigned int)(d & 0xff) << 24);
}
__device__ __forceinline__ unsigned int med3u(unsigned int a, unsigned int b,
                                              unsigned int c) {
  unsigned int m;
  asm("v_med3_u32 %0, %1, %2, %3" : "=v"(m) : "v"(a), "v"(b), "v"(c));
  return m;
}
// sorted-triple insert: 1 min + 2 med3
__device__ __forceinline__ void top3_insert(unsigned int v, unsigned int& m1,
                                            unsigned int& m2, unsigned int& m3) {
  unsigned int t2 = med3u(v, m1, m2);
  unsigned int t3 = med3u(v, m2, m3);
  m1 = v < m1 ? v : m1;
  m2 = t2;
  m3 = t3;
}

// ---- kernel 1: merged prep (w-quant 2-term + z-quant 1-term coarse) ----
__global__ __launch_bounds__(256) void prep_kernel(
    const float* __restrict__ emb, unsigned int* __restrict__ q0w,
    unsigned int* __restrict__ q1w, int* __restrict__ iwsq2,
    const float* __restrict__ z, unsigned int* __restrict__ q0z) {
  __shared__ float tile[64][65];
  int tid = threadIdx.x;
  int lane = tid & 63;
  if (blockIdx.x < 2048) {
    int row = blockIdx.x * 4 + (tid >> 6);
    const float4 v = *(const float4*)(emb + (size_t)row * DIM + lane * 4);
    float s = v.x * v.x + v.y * v.y + v.z * v.z + v.w * v.w;
    int a0 = q0_of(v.x), b0 = q0_of(v.y), c0 = q0_of(v.z), d0 = q0_of(v.w);
    q0w[row * (DIM / 4) + lane] = pack4(a0, b0, c0, d0);
    q1w[row * (DIM / 4) + lane] =
        pack4(q1_of(v.x, a0), q1_of(v.y, b0), q1_of(v.z, c0), q1_of(v.w, d0));
#pragma unroll
    for (int off = 32; off > 0; off >>= 1) s += __shfl_xor(s, off, 64);
    if (lane == 0) iwsq2[row] = (int)rintf(s * 25600.0f) + 8192;
    return;
  }
  int idx = blockIdx.x - 2048;
  int b = idx >> 6, d0 = ((idx >> 4) & 3) * 64, hw0 = (idx & 15) * 64;
  int grp = tid >> 6;
  const float* src = z + (size_t)b * DIM * HW + hw0 + lane;
#pragma unroll
  for (int i = 0; i < 16; i++) {
    int dl = grp + i * 4;
    tile[dl][lane] = src[(size_t)(d0 + dl) * HW];  // coalesced along hw
  }
  __syncthreads();
  int dq = tid & 15;  // covers 4 d's
#pragma unroll
  for (int p = 0; p < 4; p++) {
    int n = (tid >> 4) + p * 16;  // hw_local
    int a0 = q0_of(tile[dq * 4 + 0][n]), b0 = q0_of(tile[dq * 4 + 1][n]);
    int c0 = q0_of(tile[dq * 4 + 2][n]), e0 = q0_of(tile[dq * 4 + 3][n]);
    int token = b * HW + hw0 + n;
    q0z[(size_t)token * (DIM / 4) + (d0 >> 2) + dq] = pack4(a0, b0, c0, e0);
  }
}

// ---- kernel 2: 2-pass GEMM + packed-u32 top-3 per code-eighth ----
// R16 (proven): SIMD issue bandwidth is the wall (VALU+MFMA ~87% across all
// probes). 8 R0-shaped waves/block (512 thr, 256 tokens), grid 512 = 2
// blocks/CU. 85.4 -> 74.9 us measured. Per-wave: 32t x 32c/iter, late-load
// B, A in regs, 16 ds_read_b128 + 32 MFMA/iter. LDS 32 KB.
// R17: partials now TOKEN-MAJOR (token*8+kq) so kernel 3's reads coalesce.
// acc = 128*q0z.q0w + q0z.q1w ; score_int = iwsq2 - acc  (units 1/25600)
// pack = ((clamp(score)>>6)<<13) | idx13
// Spill tripwire: WRITE_SIZE must stay 2048 KB (R5 lesson).
__global__ __launch_bounds__(512) void gemm_topk_kernel(
    const signed char* __restrict__ q0z, const signed char* __restrict__ q0w,
    const signed char* __restrict__ q1w, const int* __restrict__ iwsq2,
    uint4* __restrict__ partials) {
  // [buf][arr: 0=q0w k0-127, 1=q0w k128-255, 2=q1w k0-127, 3=q1w k128-255]
  // 32 rows x 128 B per array; slot t in row holds global chunk t^(row&7)
  // (R6-R9 proven zero-conflict geometry)
  __shared__ __align__(16) signed char sB[2][4][32 * 128];  // 32 KB

  const int bid = blockIdx.x;   // 0..511
  const int kq = bid & 7;       // code eighth, pinned per XCD
  const int tg = bid >> 3;      // 0..63 token group (256 tokens)
  const int tid = threadIdx.x;
  const int lane = tid & 63, w = tid >> 6;  // 8 waves x 32 tokens
  const int c = lane & 15, quad = lane >> 4;
  const int n0 = tg * 256;
  const int k0g = kq * 1024;

  // A fragments (coarse z only): global -> registers, once
  int4v af0[2][4];
#pragma unroll
  for (int t = 0; t < 2; t++) {
    const size_t arow = (size_t)(n0 + w * 32 + t * 16 + c) * DIM;
#pragma unroll
    for (int s = 0; s < 4; s++)
      af0[t][s] = *(const int4v*)(q0z + arow + s * 64 + quad * 16);
  }

  // staging: 512 threads x 2 chunks of 16 B per tile.
  // hi = tid>>8 selects {q0w -> arrays 0,1 | q1w -> arrays 2,3}; wave-uniform.
  const int hi = tid >> 8;
  const int t2 = tid & 255;
  const int srow = t2 >> 3;                       // 0..31
  const int scl = ((t2 & 7) ^ (srow & 7)) * 16;   // swizzled source chunk
  const signed char* p = (hi ? q1w : q0w) + (size_t)(k0g + srow) * DIM + scl;
  signed char* d0s = &sB[0][hi * 2][t2 * 16];
  signed char* d1s = &sB[0][hi * 2 + 1][t2 * 16];
  async_cp16(d0s, p);
  async_cp16(d1s, p + 128);
  p += 32 * DIM;
  __syncthreads();

  unsigned int m1[8], m2[8], m3[8];
#pragma unroll
  for (int i = 0; i < 8; i++) {
    m1[i] = 0xFFFFFFFFu; m2[i] = 0xFFFFFFFFu; m3[i] = 0xFFFFFFFFu;
  }

  unsigned int idxA = (unsigned)(k0g + c);
  const int4v zero = {0, 0, 0, 0};

  for (int it = 0; it < 32; it++) {
    const int buf = it & 1;
    if (it + 1 < 32) {  // stage next 32-code tile into other buffer
      const int nb = buf ^ 1;
      async_cp16(d0s + nb * 16384, p);
      async_cp16(d1s + nb * 16384, p + 128);
      p += 32 * DIM;
    }
    const int iw0 = iwsq2[k0g + it * 32 + c];       // L1-hot
    const int iw1 = iwsq2[k0g + it * 32 + 16 + c];

    int4v a[2][2];
    // P00 (q0w; B loaded late per K-slice)
#pragma unroll
    for (int s = 0; s < 4; s++) {
      const int ph = ((((s & 1) << 2) + quad) ^ (c & 7)) * 16;
      int4v b0a = *(const int4v*)(&sB[buf][s >> 1][c * 128 + ph]);
      int4v b0b = *(const int4v*)(&sB[buf][s >> 1][(16 + c) * 128 + ph]);
      if (s == 0) {
#pragma unroll
        for (int t = 0; t < 2; t++) {
          a[t][0] = __builtin_amdgcn_mfma_i32_16x16x64_i8(af0[t][0], b0a, zero, 0, 0, 0);
          a[t][1] = __builtin_amdgcn_mfma_i32_16x16x64_i8(af0[t][0], b0b, zero, 0, 0, 0);
        }
      } else {
#pragma unroll
        for (int t = 0; t < 2; t++) {
          a[t][0] = __builtin_amdgcn_mfma_i32_16x16x64_i8(af0[t][s], b0a, a[t][0], 0, 0, 0);
          a[t][1] = __builtin_amdgcn_mfma_i32_16x16x64_i8(af0[t][s], b0b, a[t][1], 0, 0, 0);
        }
      }
    }
#pragma unroll
    for (int t = 0; t < 2; t++)
#pragma unroll
      for (int cn = 0; cn < 2; cn++)
#pragma unroll
        for (int r = 0; r < 4; r++) a[t][cn][r] <<= 7;  // 128*P00
    // P01 (af0 x q1w; b1 loaded late -> low pressure)
#pragma unroll
    for (int s = 0; s < 4; s++) {
      const int ph = ((((s & 1) << 2) + quad) ^ (c & 7)) * 16;
      int4v b1a = *(const int4v*)(&sB[buf][2 + (s >> 1)][c * 128 + ph]);
      int4v b1b = *(const int4v*)(&sB[buf][2 + (s >> 1)][(16 + c) * 128 + ph]);
#pragma unroll
      for (int t = 0; t < 2; t++) {
        a[t][0] = __builtin_amdgcn_mfma_i32_16x16x64_i8(af0[t][s], b1a, a[t][0], 0, 0, 0);
        a[t][1] = __builtin_amdgcn_mfma_i32_16x16x64_i8(af0[t][s], b1b, a[t][1], 0, 0, 0);
      }
    }
    // epilogue (C/D: col=lane&15, row=quad*4+r); min-first pair reduce
    // (pair-min can only hide a code whose PAIR PARTNER beats it in approx —
    //  partner is an effectively random code, P~0). R5-proven formulation.
#pragma unroll
    for (int t = 0; t < 2; t++) {
#pragma unroll
      for (int r = 0; r < 4; r++) {
        unsigned int s0 = (unsigned int)(iw0 - a[t][0][r]);
        unsigned int s1 = (unsigned int)(iw1 - a[t][1][r]);
        unsigned int smin = s0 < s1 ? s0 : s1;
        unsigned int idx = s1 < s0 ? idxA + 16 : idxA;
        smin = smin < 0x1FFFFFFu ? smin : 0x1FFFFFFu;
        unsigned int pk = ((smin >> 6) << 13) | idx;
        top3_insert(pk, m1[t * 4 + r], m2[t * 4 + r], m3[t * 4 + r]);
      }
    }
    idxA += 32;
    __syncthreads();  // drains next-tile staging (in flight all compute phase)
  }

  // merge top-3 across the 16 c-lanes (idx rides in low bits)
#pragma unroll
  for (int ix = 0; ix < 8; ix++) {
    unsigned int a1 = m1[ix], a2 = m2[ix], a3 = m3[ix];
#pragma unroll
    for (int off = 1; off < 16; off <<= 1) {
      unsigned int o1 = __shfl_xor(a1, off, 16);
      unsigned int o2 = __shfl_xor(a2, off, 16);
      unsigned int o3 = __shfl_xor(a3, off, 16);
      top3_insert(o1, a1, a2, a3);
      top3_insert(o2, a1, a2, a3);
      top3_insert(o3, a1, a2, a3);
    }
    m1[ix] = a1; m2[ix] = a2; m3[ix] = a3;
  }
  if (c == 0) {
#pragma unroll
    for (int t = 0; t < 2; t++) {
#pragma unroll
      for (int r = 0; r < 4; r++) {
        int token = n0 + w * 32 + t * 16 + quad * 4 + r;
        partials[(size_t)token * 8 + kq] =
            make_uint4(m1[t * 4 + r], m2[t * 4 + r], m3[t * 4 + r], 0xFFFFFFFFu);
      }
    }
  }
}

// ---- kernel 3a: filter + parallel fp64 rescore -> sid_g ----
// Token-major partials: the 8 per-token uint4 are 128 B contiguous -> wave
// filter read is one 1 KB coalesced segment. Multi-survivor tokens expand
// into a flat (token,cand) worklist; all 4 waves consume entries in
// parallel (one 64-lane fp64 dot each, identical formula + reduction order
// as the R0-proven serial version); final per-token argmin uses the same
// (s <, id <) tiebreak -> order-independent, bit-identical result.
__global__ __launch_bounds__(256) void rescore_kernel(
    const uint4* __restrict__ partials, const float* __restrict__ z,
    const float* __restrict__ emb, int* __restrict__ sid_g) {
  __shared__ int ent[768];       // (tl<<16)|id
  __shared__ double scr[768];
  __shared__ int sid[32];
  __shared__ int nent;
  const int b = blockIdx.x >> 5;
  const int hw0 = (blockIdx.x & 31) * 32;
  const int tid = threadIdx.x;
  if (tid == 0) nent = 0;
  __syncthreads();
  {
    const int tl = tid >> 3, sub = tid & 7;  // 32 tokens x 8 threads
    const int token = b * HW + hw0 + tl;
    uint4 e = partials[(size_t)token * 8 + sub];   // coalesced 1KB/wave
    unsigned int m = e.x < e.y ? e.x : e.y;
    m = e.z < m ? e.z : m;
#pragma unroll
    for (int off = 1; off < 8; off <<= 1) {
      unsigned int o = __shfl_xor(m, off, 8);
      m = o < m ? o : m;
    }
    const unsigned int thr = (m >> 13) + 1536;
    const int c0 = ((e.x >> 13) <= thr) ? 1 : 0;
    const int c1 = ((e.y >> 13) <= thr) ? 1 : 0;
    const int c2 = ((e.z >> 13) <= thr) ? 1 : 0;
    int cnt = c0 + c1 + c2;
#pragma unroll
    for (int off = 1; off < 8; off <<= 1) cnt += __shfl_xor(cnt, off, 8);
    if (cnt == 1) {
      if (sub == 0) sid[tl] = (int)(m & 0x1FFFu);
    } else {
      const int k = c0 + c1 + c2;
      if (k) {
        int j = atomicAdd(&nent, k);
        if (c0) ent[j++] = (tl << 16) | (int)(e.x & 0x1FFFu);
        if (c1) ent[j++] = (tl << 16) | (int)(e.y & 0x1FFFu);
        if (c2) ent[j] = (tl << 16) | (int)(e.z & 0x1FFFu);
      }
      if (sub == 0) sid[tl] = -1;  // unresolved
    }
  }
  __syncthreads();
  const int ne = nent;
  {
    const int w = tid >> 6, lane = tid & 63;
    for (int i = w; i < ne; i += 4) {
      const int en = ent[i];
      const int tl = en >> 16, id = en & 0x1FFF;
      float zv[4];
#pragma unroll
      for (int j = 0; j < 4; j++)
        zv[j] = z[(size_t)b * DIM * HW + (size_t)(lane * 4 + j) * HW + hw0 + tl];
      const float4 wv = *(const float4*)(emb + (size_t)id * DIM + lane * 4);
      double s = (double)wv.x * ((double)wv.x - 2.0 * (double)zv[0]) +
                 (double)wv.y * ((double)wv.y - 2.0 * (double)zv[1]) +
                 (double)wv.z * ((double)wv.z - 2.0 * (double)zv[2]) +
                 (double)wv.w * ((double)wv.w - 2.0 * (double)zv[3]);
#pragma unroll
      for (int off = 32; off > 0; off >>= 1) s += __shfl_xor(s, off, 64);
      if (lane == 0) scr[i] = s;
    }
  }
  __syncthreads();
  if (tid < 32 && sid[tid] < 0) {  // per-token argmin over its entries
    double best = 1e300;
    int bid2 = NEMB;
    for (int i = 0; i < ne; i++) {
      if ((ent[i] >> 16) == tid) {
        const double s = scr[i];
        const int id = ent[i] & 0x1FFF;
        if (s < best || (s == best && id < bid2)) {
          best = s;
          bid2 = id;
        }
      }
    }
    sid[tid] = bid2;
  }
  __syncthreads();
  if (tid < 32) sid_g[b * HW + hw0 + tid] = sid[tid];
}

// ---- kernel 3b: gather + transpose (R7-R9 proven geometry) ----
__global__ __launch_bounds__(256) void gather_kernel(
    const int* __restrict__ sid_g, const float* __restrict__ emb,
    float* __restrict__ out) {
  __shared__ float tile[32][257];
  __shared__ int sid[32];
  const int b = blockIdx.x >> 5;
  const int hw0 = (blockIdx.x & 31) * 32;
  const int tid = threadIdx.x;
  if (tid < 32) sid[tid] = sid_g[b * HW + hw0 + tid];
  __syncthreads();
  for (int i = 0; i < 32; i++)
    tile[i][tid] = emb[(size_t)sid[i] * DIM + tid];  // coalesced 1KB row loads
  __syncthreads();
  int h = tid & 31, dg = tid >> 5;
  for (int i = 0; i < 32; i++) {
    int d = i * 8 + dg;
    out[(size_t)b * DIM * HW + (size_t)d * HW + hw0 + h] = tile[h][d];
  }
}

extern "C" void kernel_launch(void* const* d_in, const int* in_sizes, int n_in,
                              void* d_out, int out_size, void* d_ws, size_t ws_size,
                              hipStream_t stream) {
  const float* z = (const float*)d_in[0];    // [16,256,32,32]
  const float* emb = (const float*)d_in[1];  // [8192,256]
  float* out = (float*)d_out;
  char* ws = (char*)d_ws;

  // ws: q0w 2M | q1w 2M | q0z 4M | iwsq2 32K | partials 2M | sid 64K
  signed char* q0w = (signed char*)(ws);
  signed char* q1w = (signed char*)(ws + 2097152);
  signed char* q0z = (signed char*)(ws + 4194304);
  int* iwsq2 = (int*)(ws + 8388608);
  uint4* partials = (uint4*)(ws + 8421376);
  int* sid_g = (int*)(ws + 10518528);

  prep_kernel<<<dim3(3072), 256, 0, stream>>>(
      emb, (unsigned int*)q0w, (unsigned int*)q1w, iwsq2, z, (unsigned int*)q0z);
  gemm_topk_kernel<<<dim3(512), 512, 0, stream>>>(q0z, q0w, q1w, iwsq2,
                                                  partials);
  rescore_kernel<<<dim3(512), 256, 0, stream>>>(partials, z, emb, sid_g);
  gather_kernel<<<dim3(512), 256, 0, stream>>>(sid_g, emb, out);
}

// Round 8
// 162.269 us; speedup vs baseline: 1.0505x; 1.0505x over previous
//
#include <hip/hip_runtime.h>
#include <stdint.h>

#define DIM 256
#define NEMB 8192
#define NTOK 16384
#define HW 1024

typedef __attribute__((ext_vector_type(4))) int int4v;

// ---- helpers ----
__device__ __forceinline__ void async_cp16(void* lds, const void* g) {
  __builtin_amdgcn_global_load_lds(
      (const __attribute__((address_space(1))) unsigned int*)g,
      (__attribute__((address_space(3))) unsigned int*)lds, 16, 0, 0);
}
// x ~ s*(q0 + q1/128), s = 1/20
__device__ __forceinline__ int q0_of(float x) {
  int q = __float2int_rn(x * 20.0f);
  return q > 127 ? 127 : (q < -127 ? -127 : q);
}
__device__ __forceinline__ int q1_of(float x, int q0) {
  float e = x * 20.0f - (float)q0;
  int q = __float2int_rn(e * 128.0f);
  return q > 127 ? 127 : (q < -127 ? -127 : q);
}
__device__ __forceinline__ unsigned int pack4(int a, int b, int c, int d) {
  return (unsigned int)(a & 0xff) | ((unsigned int)(b & 0xff) << 8) |
         ((unsigned int)(c & 0xff) << 16) | ((unsigned int)(d & 0xff) << 24);
}
__device__ __forceinline__ unsigned int med3u(unsigned int a, unsigned int b,
                                              unsigned int c) {
  unsigned int m;
  asm("v_med3_u32 %0, %1, %2, %3" : "=v"(m) : "v"(a), "v"(b), "v"(c));
  return m;
}
// sorted-triple insert: 1 min + 2 med3
__device__ __forceinline__ void top3_insert(unsigned int v, unsigned int& m1,
                                            unsigned int& m2, unsigned int& m3) {
  unsigned int t2 = med3u(v, m1, m2);
  unsigned int t3 = med3u(v, m2, m3);
  m1 = v < m1 ? v : m1;
  m2 = t2;
  m3 = t3;
}

// ---- kernel 1: merged prep (w-quant 2-term + z-quant 1-term coarse) ----
__global__ __launch_bounds__(256) void prep_kernel(
    const float* __restrict__ emb, unsigned int* __restrict__ q0w,
    unsigned int* __restrict__ q1w, int* __restrict__ iwsq2,
    const float* __restrict__ z, unsigned int* __restrict__ q0z) {
  __shared__ float tile[64][65];
  int tid = threadIdx.x;
  int lane = tid & 63;
  if (blockIdx.x < 2048) {
    int row = blockIdx.x * 4 + (tid >> 6);
    const float4 v = *(const float4*)(emb + (size_t)row * DIM + lane * 4);
    float s = v.x * v.x + v.y * v.y + v.z * v.z + v.w * v.w;
    int a0 = q0_of(v.x), b0 = q0_of(v.y), c0 = q0_of(v.z), d0 = q0_of(v.w);
    q0w[row * (DIM / 4) + lane] = pack4(a0, b0, c0, d0);
    q1w[row * (DIM / 4) + lane] =
        pack4(q1_of(v.x, a0), q1_of(v.y, b0), q1_of(v.z, c0), q1_of(v.w, d0));
#pragma unroll
    for (int off = 32; off > 0; off >>= 1) s += __shfl_xor(s, off, 64);
    if (lane == 0) iwsq2[row] = (int)rintf(s * 25600.0f) + 8192;
    return;
  }
  int idx = blockIdx.x - 2048;
  int b = idx >> 6, d0 = ((idx >> 4) & 3) * 64, hw0 = (idx & 15) * 64;
  int grp = tid >> 6;
  const float* src = z + (size_t)b * DIM * HW + hw0 + lane;
#pragma unroll
  for (int i = 0; i < 16; i++) {
    int dl = grp + i * 4;
    tile[dl][lane] = src[(size_t)(d0 + dl) * HW];  // coalesced along hw
  }
  __syncthreads();
  int dq = tid & 15;  // covers 4 d's
#pragma unroll
  for (int p = 0; p < 4; p++) {
    int n = (tid >> 4) + p * 16;  // hw_local
    int a0 = q0_of(tile[dq * 4 + 0][n]), b0 = q0_of(tile[dq * 4 + 1][n]);
    int c0 = q0_of(tile[dq * 4 + 2][n]), e0 = q0_of(tile[dq * 4 + 3][n]);
    int token = b * HW + hw0 + n;
    q0z[(size_t)token * (DIM / 4) + (d0 >> 2) + dq] = pack4(a0, b0, c0, e0);
  }
}

// ---- kernel 2: 2-pass GEMM + packed-u32 top-3 per code-eighth ----
// R16 (proven): SIMD issue bandwidth is the wall (VALU+MFMA ~87% across all
// probes). 8 R0-shaped waves/block (512 thr, 256 tokens), grid 512 = 2
// blocks/CU. Per-wave: 32t x 32c/iter, late-load B, A in regs, 16
// ds_read_b128 + 32 MFMA/iter. LDS 32 KB. Measured 72.5 us (R7).
// R17: partials TOKEN-MAJOR (token*8+kq) so kernel 3's reads coalesce.
// (WRITE_SIZE 4096 KB = 16B@128B-stride cacheline amplification, NOT spill.)
// acc = 128*q0z.q0w + q0z.q1w ; score_int = iwsq2 - acc  (units 1/25600)
// pack = ((clamp(score)>>6)<<13) | idx13
__global__ __launch_bounds__(512) void gemm_topk_kernel(
    const signed char* __restrict__ q0z, const signed char* __restrict__ q0w,
    const signed char* __restrict__ q1w, const int* __restrict__ iwsq2,
    uint4* __restrict__ partials) {
  // [buf][arr: 0=q0w k0-127, 1=q0w k128-255, 2=q1w k0-127, 3=q1w k128-255]
  // 32 rows x 128 B per array; slot t in row holds global chunk t^(row&7)
  // (R6-R9 proven zero-conflict geometry)
  __shared__ __align__(16) signed char sB[2][4][32 * 128];  // 32 KB

  const int bid = blockIdx.x;   // 0..511
  const int kq = bid & 7;       // code eighth, pinned per XCD
  const int tg = bid >> 3;      // 0..63 token group (256 tokens)
  const int tid = threadIdx.x;
  const int lane = tid & 63, w = tid >> 6;  // 8 waves x 32 tokens
  const int c = lane & 15, quad = lane >> 4;
  const int n0 = tg * 256;
  const int k0g = kq * 1024;

  // A fragments (coarse z only): global -> registers, once
  int4v af0[2][4];
#pragma unroll
  for (int t = 0; t < 2; t++) {
    const size_t arow = (size_t)(n0 + w * 32 + t * 16 + c) * DIM;
#pragma unroll
    for (int s = 0; s < 4; s++)
      af0[t][s] = *(const int4v*)(q0z + arow + s * 64 + quad * 16);
  }

  // staging: 512 threads x 2 chunks of 16 B per tile.
  // hi = tid>>8 selects {q0w -> arrays 0,1 | q1w -> arrays 2,3}; wave-uniform.
  const int hi = tid >> 8;
  const int t2 = tid & 255;
  const int srow = t2 >> 3;                       // 0..31
  const int scl = ((t2 & 7) ^ (srow & 7)) * 16;   // swizzled source chunk
  const signed char* p = (hi ? q1w : q0w) + (size_t)(k0g + srow) * DIM + scl;
  signed char* d0s = &sB[0][hi * 2][t2 * 16];
  signed char* d1s = &sB[0][hi * 2 + 1][t2 * 16];
  async_cp16(d0s, p);
  async_cp16(d1s, p + 128);
  p += 32 * DIM;
  __syncthreads();

  unsigned int m1[8], m2[8], m3[8];
#pragma unroll
  for (int i = 0; i < 8; i++) {
    m1[i] = 0xFFFFFFFFu; m2[i] = 0xFFFFFFFFu; m3[i] = 0xFFFFFFFFu;
  }

  unsigned int idxA = (unsigned)(k0g + c);
  const int4v zero = {0, 0, 0, 0};

  for (int it = 0; it < 32; it++) {
    const int buf = it & 1;
    if (it + 1 < 32) {  // stage next 32-code tile into other buffer
      const int nb = buf ^ 1;
      async_cp16(d0s + nb * 16384, p);
      async_cp16(d1s + nb * 16384, p + 128);
      p += 32 * DIM;
    }
    const int iw0 = iwsq2[k0g + it * 32 + c];       // L1-hot
    const int iw1 = iwsq2[k0g + it * 32 + 16 + c];

    int4v a[2][2];
    // P00 (q0w; B loaded late per K-slice)
#pragma unroll
    for (int s = 0; s < 4; s++) {
      const int ph = ((((s & 1) << 2) + quad) ^ (c & 7)) * 16;
      int4v b0a = *(const int4v*)(&sB[buf][s >> 1][c * 128 + ph]);
      int4v b0b = *(const int4v*)(&sB[buf][s >> 1][(16 + c) * 128 + ph]);
      if (s == 0) {
#pragma unroll
        for (int t = 0; t < 2; t++) {
          a[t][0] = __builtin_amdgcn_mfma_i32_16x16x64_i8(af0[t][0], b0a, zero, 0, 0, 0);
          a[t][1] = __builtin_amdgcn_mfma_i32_16x16x64_i8(af0[t][0], b0b, zero, 0, 0, 0);
        }
      } else {
#pragma unroll
        for (int t = 0; t < 2; t++) {
          a[t][0] = __builtin_amdgcn_mfma_i32_16x16x64_i8(af0[t][s], b0a, a[t][0], 0, 0, 0);
          a[t][1] = __builtin_amdgcn_mfma_i32_16x16x64_i8(af0[t][s], b0b, a[t][1], 0, 0, 0);
        }
      }
    }
#pragma unroll
    for (int t = 0; t < 2; t++)
#pragma unroll
      for (int cn = 0; cn < 2; cn++)
#pragma unroll
        for (int r = 0; r < 4; r++) a[t][cn][r] <<= 7;  // 128*P00
    // P01 (af0 x q1w; b1 loaded late -> low pressure)
#pragma unroll
    for (int s = 0; s < 4; s++) {
      const int ph = ((((s & 1) << 2) + quad) ^ (c & 7)) * 16;
      int4v b1a = *(const int4v*)(&sB[buf][2 + (s >> 1)][c * 128 + ph]);
      int4v b1b = *(const int4v*)(&sB[buf][2 + (s >> 1)][(16 + c) * 128 + ph]);
#pragma unroll
      for (int t = 0; t < 2; t++) {
        a[t][0] = __builtin_amdgcn_mfma_i32_16x16x64_i8(af0[t][s], b1a, a[t][0], 0, 0, 0);
        a[t][1] = __builtin_amdgcn_mfma_i32_16x16x64_i8(af0[t][s], b1b, a[t][1], 0, 0, 0);
      }
    }
    // epilogue (C/D: col=lane&15, row=quad*4+r); min-first pair reduce
    // (pair-min can only hide a code whose PAIR PARTNER beats it in approx —
    //  partner is an effectively random code, P~0). R5-proven formulation.
#pragma unroll
    for (int t = 0; t < 2; t++) {
#pragma unroll
      for (int r = 0; r < 4; r++) {
        unsigned int s0 = (unsigned int)(iw0 - a[t][0][r]);
        unsigned int s1 = (unsigned int)(iw1 - a[t][1][r]);
        unsigned int smin = s0 < s1 ? s0 : s1;
        unsigned int idx = s1 < s0 ? idxA + 16 : idxA;
        smin = smin < 0x1FFFFFFu ? smin : 0x1FFFFFFu;
        unsigned int pk = ((smin >> 6) << 13) | idx;
        top3_insert(pk, m1[t * 4 + r], m2[t * 4 + r], m3[t * 4 + r]);
      }
    }
    idxA += 32;
    __syncthreads();  // drains next-tile staging (in flight all compute phase)
  }

  // merge top-3 across the 16 c-lanes (idx rides in low bits)
#pragma unroll
  for (int ix = 0; ix < 8; ix++) {
    unsigned int a1 = m1[ix], a2 = m2[ix], a3 = m3[ix];
#pragma unroll
    for (int off = 1; off < 16; off <<= 1) {
      unsigned int o1 = __shfl_xor(a1, off, 16);
      unsigned int o2 = __shfl_xor(a2, off, 16);
      unsigned int o3 = __shfl_xor(a3, off, 16);
      top3_insert(o1, a1, a2, a3);
      top3_insert(o2, a1, a2, a3);
      top3_insert(o3, a1, a2, a3);
    }
    m1[ix] = a1; m2[ix] = a2; m3[ix] = a3;
  }
  if (c == 0) {
#pragma unroll
    for (int t = 0; t < 2; t++) {
#pragma unroll
      for (int r = 0; r < 4; r++) {
        int token = n0 + w * 32 + t * 16 + quad * 4 + r;
        partials[(size_t)token * 8 + kq] =
            make_uint4(m1[t * 4 + r], m2[t * 4 + r], m3[t * 4 + r], 0xFFFFFFFFu);
      }
    }
  }
}

// ---- kernel 3: fused filter/rescore + gather/transpose (R18) ----
// R6 structure (3 launches, z loaded once per worklist token, serial
// wave-uniform candidate loop) + R7's token-major partials so BOTH the
// filter read (1KB contiguous/wave) and the fallback's 24-candidate read
// (128B contiguous/token) coalesce. Survivor = within 1536 packed units of
// min; 1 survivor -> zero extra loads; else fp64 rescore via LDS worklist.
__global__ __launch_bounds__(256) void rescore_gather_kernel(
    const uint4* __restrict__ partials, const float* __restrict__ z,
    const float* __restrict__ emb, float* __restrict__ out) {
  __shared__ float tile[32][257];
  __shared__ int sid[32];
  __shared__ int wl[32];
  __shared__ int nwl;
  const int b = blockIdx.x >> 5;
  const int hw0 = (blockIdx.x & 31) * 32;
  const int tid = threadIdx.x;
  if (tid == 0) nwl = 0;
  __syncthreads();
  {
    const int tl = tid >> 3, sub = tid & 7;  // 32 tokens x 8 threads
    const int token = b * HW + hw0 + tl;
    uint4 e = partials[(size_t)token * 8 + sub];   // coalesced 1KB/wave
    unsigned int m = e.x < e.y ? e.x : e.y;
    m = e.z < m ? e.z : m;
#pragma unroll
    for (int off = 1; off < 8; off <<= 1) {
      unsigned int o = __shfl_xor(m, off, 8);
      m = o < m ? o : m;
    }
    const unsigned int thr = (m >> 13) + 1536;
    int cnt = (((e.x >> 13) <= thr) ? 1 : 0) + (((e.y >> 13) <= thr) ? 1 : 0) +
              (((e.z >> 13) <= thr) ? 1 : 0);
#pragma unroll
    for (int off = 1; off < 8; off <<= 1) cnt += __shfl_xor(cnt, off, 8);
    if (sub == 0) {
      if (cnt == 1) {
        sid[tl] = (int)(m & 0x1FFFu);
      } else {
        int i = atomicAdd(&nwl, 1);
        wl[i] = tl;
      }
    }
  }
  __syncthreads();
  // fallback: one wave per worklist entry, exact fp64 over survivors
  {
    const int w = tid >> 6, lane = tid & 63;
    for (int i = w; i < nwl; i += 4) {
      const int tl = wl[i];
      const int token = b * HW + hw0 + tl;
      unsigned int p[24];
#pragma unroll
      for (int q = 0; q < 8; q++) {
        uint4 t = partials[(size_t)token * 8 + q];  // 128B contiguous
        p[q * 3] = t.x;
        p[q * 3 + 1] = t.y;
        p[q * 3 + 2] = t.z;
      }
      unsigned int smin = p[0];
#pragma unroll
      for (int q = 1; q < 24; q++) smin = p[q] < smin ? p[q] : smin;
      const unsigned int thr = (smin >> 13) + 1536;
      float zv[4];
#pragma unroll
      for (int j = 0; j < 4; j++)
        zv[j] = z[(size_t)b * DIM * HW + (size_t)(lane * 4 + j) * HW + hw0 + tl];
      double best = 1e300;
      int bid2 = NEMB;
#pragma unroll
      for (int q = 0; q < 24; q++) {
        if ((p[q] >> 13) <= thr) {  // wave-uniform
          int id = (int)(p[q] & 0x1FFFu);
          const float4 wv = *(const float4*)(emb + (size_t)id * DIM + lane * 4);
          double s = (double)wv.x * ((double)wv.x - 2.0 * (double)zv[0]) +
                     (double)wv.y * ((double)wv.y - 2.0 * (double)zv[1]) +
                     (double)wv.z * ((double)wv.z - 2.0 * (double)zv[2]) +
                     (double)wv.w * ((double)wv.w - 2.0 * (double)zv[3]);
#pragma unroll
          for (int off = 32; off > 0; off >>= 1) s += __shfl_xor(s, off, 64);
          if (s < best || (s == best && id < bid2)) {
            best = s;
            bid2 = id;
          }
        }
      }
      if (lane == 0) sid[tl] = bid2;
    }
  }
  __syncthreads();
  // gather + transpose (R7-R9 proven)
  for (int i = 0; i < 32; i++)
    tile[i][tid] = emb[(size_t)sid[i] * DIM + tid];  // coalesced 1KB row loads
  __syncthreads();
  int h = tid & 31, dg = tid >> 5;
  for (int i = 0; i < 32; i++) {
    int d = i * 8 + dg;
    out[(size_t)b * DIM * HW + (size_t)d * HW + hw0 + h] = tile[h][d];
  }
}

extern "C" void kernel_launch(void* const* d_in, const int* in_sizes, int n_in,
                              void* d_out, int out_size, void* d_ws, size_t ws_size,
                              hipStream_t stream) {
  const float* z = (const float*)d_in[0];    // [16,256,32,32]
  const float* emb = (const float*)d_in[1];  // [8192,256]
  float* out = (float*)d_out;
  char* ws = (char*)d_ws;

  // ws: q0w 2M | q1w 2M | q0z 4M | iwsq2 32K | partials 2M
  signed char* q0w = (signed char*)(ws);
  signed char* q1w = (signed char*)(ws + 2097152);
  signed char* q0z = (signed char*)(ws + 4194304);
  int* iwsq2 = (int*)(ws + 8388608);
  uint4* partials = (uint4*)(ws + 8421376);

  prep_kernel<<<dim3(3072), 256, 0, stream>>>(
      emb, (unsigned int*)q0w, (unsigned int*)q1w, iwsq2, z, (unsigned int*)q0z);
  gemm_topk_kernel<<<dim3(512), 512, 0, stream>>>(q0z, q0w, q1w, iwsq2,
                                                  partials);
  rescore_gather_kernel<<<dim3(512), 256, 0, stream>>>(partials, z, emb, out);
}

// Round 9
// 157.239 us; speedup vs baseline: 1.0841x; 1.0320x over previous
//
#include <hip/hip_runtime.h>
#include <stdint.h>

#define DIM 256
#define NEMB 8192
#define NTOK 16384
#define HW 1024

typedef __attribute__((ext_vector_type(4))) int int4v;

// ---- helpers ----
__device__ __forceinline__ void async_cp16(void* lds, const void* g) {
  __builtin_amdgcn_global_load_lds(
      (const __attribute__((address_space(1))) unsigned int*)g,
      (__attribute__((address_space(3))) unsigned int*)lds, 16, 0, 0);
}
// x ~ s*(q0 + q1/128), s = 1/20
__device__ __forceinline__ int q0_of(float x) {
  int q = __float2int_rn(x * 20.0f);
  return q > 127 ? 127 : (q < -127 ? -127 : q);
}
__device__ __forceinline__ int q1_of(float x, int q0) {
  float e = x * 20.0f - (float)q0;
  int q = __float2int_rn(e * 128.0f);
  return q > 127 ? 127 : (q < -127 ? -127 : q);
}
__device__ __forceinline__ unsigned int pack4(int a, int b, int c, int d) {
  return (unsigned int)(a & 0xff) | ((unsigned int)(b & 0xff) << 8) |
         ((unsigned int)(c & 0xff) << 16) | ((unsigned int)(d & 0xff) << 24);
}
__device__ __forceinline__ unsigned int med3u(unsigned int a, unsigned int b,
                                              unsigned int c) {
  unsigned int m;
  asm("v_med3_u32 %0, %1, %2, %3" : "=v"(m) : "v"(a), "v"(b), "v"(c));
  return m;
}
// sorted-triple insert: 1 min + 2 med3
__device__ __forceinline__ void top3_insert(unsigned int v, unsigned int& m1,
                                            unsigned int& m2, unsigned int& m3) {
  unsigned int t2 = med3u(v, m1, m2);
  unsigned int t3 = med3u(v, m2, m3);
  m1 = v < m1 ? v : m1;
  m2 = t2;
  m3 = t3;
}

// ---- kernel 1: merged prep (w-quant 2-term + z-quant 1-term coarse) ----
__global__ __launch_bounds__(256) void prep_kernel(
    const float* __restrict__ emb, unsigned int* __restrict__ q0w,
    unsigned int* __restrict__ q1w, int* __restrict__ iwsq2,
    const float* __restrict__ z, unsigned int* __restrict__ q0z) {
  __shared__ float tile[64][65];
  int tid = threadIdx.x;
  int lane = tid & 63;
  if (blockIdx.x < 2048) {
    int row = blockIdx.x * 4 + (tid >> 6);
    const float4 v = *(const float4*)(emb + (size_t)row * DIM + lane * 4);
    float s = v.x * v.x + v.y * v.y + v.z * v.z + v.w * v.w;
    int a0 = q0_of(v.x), b0 = q0_of(v.y), c0 = q0_of(v.z), d0 = q0_of(v.w);
    q0w[row * (DIM / 4) + lane] = pack4(a0, b0, c0, d0);
    q1w[row * (DIM / 4) + lane] =
        pack4(q1_of(v.x, a0), q1_of(v.y, b0), q1_of(v.z, c0), q1_of(v.w, d0));
#pragma unroll
    for (int off = 32; off > 0; off >>= 1) s += __shfl_xor(s, off, 64);
    if (lane == 0) iwsq2[row] = (int)rintf(s * 25600.0f) + 8192;
    return;
  }
  int idx = blockIdx.x - 2048;
  int b = idx >> 6, d0 = ((idx >> 4) & 3) * 64, hw0 = (idx & 15) * 64;
  int grp = tid >> 6;
  const float* src = z + (size_t)b * DIM * HW + hw0 + lane;
#pragma unroll
  for (int i = 0; i < 16; i++) {
    int dl = grp + i * 4;
    tile[dl][lane] = src[(size_t)(d0 + dl) * HW];  // coalesced along hw
  }
  __syncthreads();
  int dq = tid & 15;  // covers 4 d's
#pragma unroll
  for (int p = 0; p < 4; p++) {
    int n = (tid >> 4) + p * 16;  // hw_local
    int a0 = q0_of(tile[dq * 4 + 0][n]), b0 = q0_of(tile[dq * 4 + 1][n]);
    int c0 = q0_of(tile[dq * 4 + 2][n]), e0 = q0_of(tile[dq * 4 + 3][n]);
    int token = b * HW + hw0 + n;
    q0z[(size_t)token * (DIM / 4) + (d0 >> 2) + dq] = pack4(a0, b0, c0, e0);
  }
}

// ---- kernel 2: 2-pass GEMM + packed-u32 top-3 per code-eighth ----
// R16 (proven): SIMD issue bandwidth is the wall (VALU+MFMA ~87% across all
// probes). 8 R0-shaped waves/block (512 thr, 256 tokens), grid 512 = 2
// blocks/CU. Per-wave: 32t x 32c/iter, late-load B, A in regs, 16
// ds_read_b128 + 32 MFMA/iter. LDS 32 KB. Measured 72.5-75 us (R7/R8).
// R17: partials TOKEN-MAJOR (token*8+kq) so kernel 3's reads coalesce.
// (WRITE_SIZE 4096 KB = 16B@128B-stride cacheline amplification, NOT spill.)
// acc = 128*q0z.q0w + q0z.q1w ; score_int = iwsq2 - acc  (units 1/25600)
// pack = ((clamp(score)>>6)<<13) | idx13
__global__ __launch_bounds__(512) void gemm_topk_kernel(
    const signed char* __restrict__ q0z, const signed char* __restrict__ q0w,
    const signed char* __restrict__ q1w, const int* __restrict__ iwsq2,
    uint4* __restrict__ partials) {
  // [buf][arr: 0=q0w k0-127, 1=q0w k128-255, 2=q1w k0-127, 3=q1w k128-255]
  // 32 rows x 128 B per array; slot t in row holds global chunk t^(row&7)
  // (R6-R9 proven zero-conflict geometry)
  __shared__ __align__(16) signed char sB[2][4][32 * 128];  // 32 KB

  const int bid = blockIdx.x;   // 0..511
  const int kq = bid & 7;       // code eighth, pinned per XCD
  const int tg = bid >> 3;      // 0..63 token group (256 tokens)
  const int tid = threadIdx.x;
  const int lane = tid & 63, w = tid >> 6;  // 8 waves x 32 tokens
  const int c = lane & 15, quad = lane >> 4;
  const int n0 = tg * 256;
  const int k0g = kq * 1024;

  // A fragments (coarse z only): global -> registers, once
  int4v af0[2][4];
#pragma unroll
  for (int t = 0; t < 2; t++) {
    const size_t arow = (size_t)(n0 + w * 32 + t * 16 + c) * DIM;
#pragma unroll
    for (int s = 0; s < 4; s++)
      af0[t][s] = *(const int4v*)(q0z + arow + s * 64 + quad * 16);
  }

  // staging: 512 threads x 2 chunks of 16 B per tile.
  // hi = tid>>8 selects {q0w -> arrays 0,1 | q1w -> arrays 2,3}; wave-uniform.
  const int hi = tid >> 8;
  const int t2 = tid & 255;
  const int srow = t2 >> 3;                       // 0..31
  const int scl = ((t2 & 7) ^ (srow & 7)) * 16;   // swizzled source chunk
  const signed char* p = (hi ? q1w : q0w) + (size_t)(k0g + srow) * DIM + scl;
  signed char* d0s = &sB[0][hi * 2][t2 * 16];
  signed char* d1s = &sB[0][hi * 2 + 1][t2 * 16];
  async_cp16(d0s, p);
  async_cp16(d1s, p + 128);
  p += 32 * DIM;
  __syncthreads();

  unsigned int m1[8], m2[8], m3[8];
#pragma unroll
  for (int i = 0; i < 8; i++) {
    m1[i] = 0xFFFFFFFFu; m2[i] = 0xFFFFFFFFu; m3[i] = 0xFFFFFFFFu;
  }

  unsigned int idxA = (unsigned)(k0g + c);
  const int4v zero = {0, 0, 0, 0};

  for (int it = 0; it < 32; it++) {
    const int buf = it & 1;
    if (it + 1 < 32) {  // stage next 32-code tile into other buffer
      const int nb = buf ^ 1;
      async_cp16(d0s + nb * 16384, p);
      async_cp16(d1s + nb * 16384, p + 128);
      p += 32 * DIM;
    }
    const int iw0 = iwsq2[k0g + it * 32 + c];       // L1-hot
    const int iw1 = iwsq2[k0g + it * 32 + 16 + c];

    int4v a[2][2];
    // P00 (q0w; B loaded late per K-slice)
#pragma unroll
    for (int s = 0; s < 4; s++) {
      const int ph = ((((s & 1) << 2) + quad) ^ (c & 7)) * 16;
      int4v b0a = *(const int4v*)(&sB[buf][s >> 1][c * 128 + ph]);
      int4v b0b = *(const int4v*)(&sB[buf][s >> 1][(16 + c) * 128 + ph]);
      if (s == 0) {
#pragma unroll
        for (int t = 0; t < 2; t++) {
          a[t][0] = __builtin_amdgcn_mfma_i32_16x16x64_i8(af0[t][0], b0a, zero, 0, 0, 0);
          a[t][1] = __builtin_amdgcn_mfma_i32_16x16x64_i8(af0[t][0], b0b, zero, 0, 0, 0);
        }
      } else {
#pragma unroll
        for (int t = 0; t < 2; t++) {
          a[t][0] = __builtin_amdgcn_mfma_i32_16x16x64_i8(af0[t][s], b0a, a[t][0], 0, 0, 0);
          a[t][1] = __builtin_amdgcn_mfma_i32_16x16x64_i8(af0[t][s], b0b, a[t][1], 0, 0, 0);
        }
      }
    }
#pragma unroll
    for (int t = 0; t < 2; t++)
#pragma unroll
      for (int cn = 0; cn < 2; cn++)
#pragma unroll
        for (int r = 0; r < 4; r++) a[t][cn][r] <<= 7;  // 128*P00
    // P01 (af0 x q1w; b1 loaded late -> low pressure)
#pragma unroll
    for (int s = 0; s < 4; s++) {
      const int ph = ((((s & 1) << 2) + quad) ^ (c & 7)) * 16;
      int4v b1a = *(const int4v*)(&sB[buf][2 + (s >> 1)][c * 128 + ph]);
      int4v b1b = *(const int4v*)(&sB[buf][2 + (s >> 1)][(16 + c) * 128 + ph]);
#pragma unroll
      for (int t = 0; t < 2; t++) {
        a[t][0] = __builtin_amdgcn_mfma_i32_16x16x64_i8(af0[t][s], b1a, a[t][0], 0, 0, 0);
        a[t][1] = __builtin_amdgcn_mfma_i32_16x16x64_i8(af0[t][s], b1b, a[t][1], 0, 0, 0);
      }
    }
    // epilogue (C/D: col=lane&15, row=quad*4+r); min-first pair reduce
    // (pair-min can only hide a code whose PAIR PARTNER beats it in approx —
    //  partner is an effectively random code, P~0). R5-proven formulation.
#pragma unroll
    for (int t = 0; t < 2; t++) {
#pragma unroll
      for (int r = 0; r < 4; r++) {
        unsigned int s0 = (unsigned int)(iw0 - a[t][0][r]);
        unsigned int s1 = (unsigned int)(iw1 - a[t][1][r]);
        unsigned int smin = s0 < s1 ? s0 : s1;
        unsigned int idx = s1 < s0 ? idxA + 16 : idxA;
        smin = smin < 0x1FFFFFFu ? smin : 0x1FFFFFFu;
        unsigned int pk = ((smin >> 6) << 13) | idx;
        top3_insert(pk, m1[t * 4 + r], m2[t * 4 + r], m3[t * 4 + r]);
      }
    }
    idxA += 32;
    __syncthreads();  // drains next-tile staging (in flight all compute phase)
  }

  // merge top-3 across the 16 c-lanes (idx rides in low bits)
#pragma unroll
  for (int ix = 0; ix < 8; ix++) {
    unsigned int a1 = m1[ix], a2 = m2[ix], a3 = m3[ix];
#pragma unroll
    for (int off = 1; off < 16; off <<= 1) {
      unsigned int o1 = __shfl_xor(a1, off, 16);
      unsigned int o2 = __shfl_xor(a2, off, 16);
      unsigned int o3 = __shfl_xor(a3, off, 16);
      top3_insert(o1, a1, a2, a3);
      top3_insert(o2, a1, a2, a3);
      top3_insert(o3, a1, a2, a3);
    }
    m1[ix] = a1; m2[ix] = a2; m3[ix] = a3;
  }
  if (c == 0) {
#pragma unroll
    for (int t = 0; t < 2; t++) {
#pragma unroll
      for (int r = 0; r < 4; r++) {
        int token = n0 + w * 32 + t * 16 + quad * 4 + r;
        partials[(size_t)token * 8 + kq] =
            make_uint4(m1[t * 4 + r], m2[t * 4 + r], m3[t * 4 + r], 0xFFFFFFFFu);
      }
    }
  }
}

// ---- kernel 3: fused filter/rescore + gather/transpose (R19) ----
// R8 result: coalescing partials reads was NEUTRAL -> rescore cost is not
// partials traffic. Remaining big term: fallback's z read put 64 lanes at
// 4KB stride (256 scattered dwords/token, 16x line amplification + ~1us
// serial latency per multi-survivor token). Fix: stage the block's z slab
// z[b, :, hw0:hw0+32) = 32KB ONCE into the (reused) gather tile via
// coalesced float4 rows (thread d=tid reads its 32-float row, every byte
// used), then fallback reads zv from LDS. Values bit-identical -> fp64
// rescore unchanged -> absmax 0 preserved. Gather reuses tile after the
// existing barrier.
__global__ __launch_bounds__(256) void rescore_gather_kernel(
    const uint4* __restrict__ partials, const float* __restrict__ z,
    const float* __restrict__ emb, float* __restrict__ out) {
  __shared__ float tile[32][257];
  __shared__ int sid[32];
  __shared__ int wl[32];
  __shared__ int nwl;
  const int b = blockIdx.x >> 5;
  const int hw0 = (blockIdx.x & 31) * 32;
  const int tid = threadIdx.x;
  if (tid == 0) nwl = 0;
  __syncthreads();
  {
    const int tl = tid >> 3, sub = tid & 7;  // 32 tokens x 8 threads
    const int token = b * HW + hw0 + tl;
    uint4 e = partials[(size_t)token * 8 + sub];   // coalesced 1KB/wave
    unsigned int m = e.x < e.y ? e.x : e.y;
    m = e.z < m ? e.z : m;
#pragma unroll
    for (int off = 1; off < 8; off <<= 1) {
      unsigned int o = __shfl_xor(m, off, 8);
      m = o < m ? o : m;
    }
    const unsigned int thr = (m >> 13) + 1536;
    int cnt = (((e.x >> 13) <= thr) ? 1 : 0) + (((e.y >> 13) <= thr) ? 1 : 0) +
              (((e.z >> 13) <= thr) ? 1 : 0);
#pragma unroll
    for (int off = 1; off < 8; off <<= 1) cnt += __shfl_xor(cnt, off, 8);
    if (sub == 0) {
      if (cnt == 1) {
        sid[tl] = (int)(m & 0x1FFFu);
      } else {
        int i = atomicAdd(&nwl, 1);
        wl[i] = tl;
      }
    }
  }
  __syncthreads();
  // stage z slab: tile[h][d] = z[b, d, hw0+h]; thread d=tid reads its
  // 32-float row as 8 float4 (128B/lane, every fetched byte used); LDS
  // writes are lane-consecutive per instr (conflict-free).
  {
    const float* zp = z + (size_t)b * DIM * HW + (size_t)tid * HW + hw0;
#pragma unroll
    for (int h4 = 0; h4 < 8; h4++) {
      const float4 v = *(const float4*)(zp + h4 * 4);
      tile[h4 * 4 + 0][tid] = v.x;
      tile[h4 * 4 + 1][tid] = v.y;
      tile[h4 * 4 + 2][tid] = v.z;
      tile[h4 * 4 + 3][tid] = v.w;
    }
  }
  __syncthreads();
  // fallback: one wave per worklist entry, exact fp64 over survivors
  {
    const int w = tid >> 6, lane = tid & 63;
    for (int i = w; i < nwl; i += 4) {
      const int tl = wl[i];
      const int token = b * HW + hw0 + tl;
      unsigned int p[24];
#pragma unroll
      for (int q = 0; q < 8; q++) {
        uint4 t = partials[(size_t)token * 8 + q];  // 128B contiguous
        p[q * 3] = t.x;
        p[q * 3 + 1] = t.y;
        p[q * 3 + 2] = t.z;
      }
      unsigned int smin = p[0];
#pragma unroll
      for (int q = 1; q < 24; q++) smin = p[q] < smin ? p[q] : smin;
      const unsigned int thr = (smin >> 13) + 1536;
      float zv[4];
#pragma unroll
      for (int j = 0; j < 4; j++) zv[j] = tile[tl][lane * 4 + j];  // LDS
      double best = 1e300;
      int bid2 = NEMB;
#pragma unroll
      for (int q = 0; q < 24; q++) {
        if ((p[q] >> 13) <= thr) {  // wave-uniform
          int id = (int)(p[q] & 0x1FFFu);
          const float4 wv = *(const float4*)(emb + (size_t)id * DIM + lane * 4);
          double s = (double)wv.x * ((double)wv.x - 2.0 * (double)zv[0]) +
                     (double)wv.y * ((double)wv.y - 2.0 * (double)zv[1]) +
                     (double)wv.z * ((double)wv.z - 2.0 * (double)zv[2]) +
                     (double)wv.w * ((double)wv.w - 2.0 * (double)zv[3]);
#pragma unroll
          for (int off = 32; off > 0; off >>= 1) s += __shfl_xor(s, off, 64);
          if (s < best || (s == best && id < bid2)) {
            best = s;
            bid2 = id;
          }
        }
      }
      if (lane == 0) sid[tl] = bid2;
    }
  }
  __syncthreads();
  // gather + transpose (R7-R9 proven; tile reused, overwrite after barrier)
  for (int i = 0; i < 32; i++)
    tile[i][tid] = emb[(size_t)sid[i] * DIM + tid];  // coalesced 1KB row loads
  __syncthreads();
  int h = tid & 31, dg = tid >> 5;
  for (int i = 0; i < 32; i++) {
    int d = i * 8 + dg;
    out[(size_t)b * DIM * HW + (size_t)d * HW + hw0 + h] = tile[h][d];
  }
}

extern "C" void kernel_launch(void* const* d_in, const int* in_sizes, int n_in,
                              void* d_out, int out_size, void* d_ws, size_t ws_size,
                              hipStream_t stream) {
  const float* z = (const float*)d_in[0];    // [16,256,32,32]
  const float* emb = (const float*)d_in[1];  // [8192,256]
  float* out = (float*)d_out;
  char* ws = (char*)d_ws;

  // ws: q0w 2M | q1w 2M | q0z 4M | iwsq2 32K | partials 2M
  signed char* q0w = (signed char*)(ws);
  signed char* q1w = (signed char*)(ws + 2097152);
  signed char* q0z = (signed char*)(ws + 4194304);
  int* iwsq2 = (int*)(ws + 8388608);
  uint4* partials = (uint4*)(ws + 8421376);

  prep_kernel<<<dim3(3072), 256, 0, stream>>>(
      emb, (unsigned int*)q0w, (unsigned int*)q1w, iwsq2, z, (unsigned int*)q0z);
  gemm_topk_kernel<<<dim3(512), 512, 0, stream>>>(q0z, q0w, q1w, iwsq2,
                                                  partials);
  rescore_gather_kernel<<<dim3(512), 256, 0, stream>>>(partials, z, emb, out);
}